// Round 14
// baseline (119.357 us; speedup 1.0000x reference)
//
#include <hip/hip_runtime.h>
#include <hip/hip_bf16.h>

#define NPIX 4096
#define NCH  256

typedef __attribute__((ext_vector_type(8))) short short8;
typedef __attribute__((ext_vector_type(4))) short s16x4;
typedef __attribute__((ext_vector_type(16))) float f32x16;
typedef __attribute__((ext_vector_type(8))) int i32x8;

// 4x 8-byte k-chunks -> one K=64 f8f6f4 operand (8 VGPRs)
union Frag64 { long l[4]; i32x8 v; };

#define SC1 0x7F7F7F7F  // E8M0 scale bytes = 127 -> scale 1.0 (all blocks)

// pack 4 f32 -> 4 fp8 e4m3 bytes (OCP on gfx950), byte0=a .. byte3=d
__device__ inline unsigned int pkfp8x4(float a, float b, float c, float d) {
    int w = __builtin_amdgcn_cvt_pk_fp8_f32(a, b, 0, false);
    w = __builtin_amdgcn_cvt_pk_fp8_f32(c, d, w, true);
    return (unsigned int)w;
}

__device__ inline unsigned char fp8b(float a) {
    return (unsigned char)(__builtin_amdgcn_cvt_pk_fp8_f32(a, a, 0, false) & 0xff);
}

__device__ inline float bperm(int srclane, float v) {
    return __int_as_float(__builtin_amdgcn_ds_bpermute(
        srclane << 2, __float_as_int(v)));
}

__device__ inline unsigned short bfbits(float f) {
    __hip_bfloat16 h = __float2bfloat16(f);
    return *reinterpret_cast<unsigned short*>(&h);
}

// Raw hw exp2 (no denormal fixup). MUST be the compiler-visible intrinsic:
// inline-asm v_exp_f32 skips TRANS-hazard s_nop insertion -> NaN (r10).
#if __has_builtin(__builtin_amdgcn_exp2f)
__device__ inline float exp2_raw(float x) { return __builtin_amdgcn_exp2f(x); }
#else
__device__ inline float exp2_raw(float x) { return __builtin_exp2f(x); }
#endif

// Barrier WITHOUT the vmcnt(0) drain __syncthreads would emit: only LDS
// (lgkmcnt) ordering is needed for the ps handoff; global register loads
// stay in flight across phases.
__device__ inline void barrier_nodrain() {
    __builtin_amdgcn_sched_barrier(0);
    asm volatile("s_waitcnt lgkmcnt(0)" ::: "memory");
    __builtin_amdgcn_s_barrier();
    __builtin_amdgcn_sched_barrier(0);
}

// ---------------------------------------------------------------------------
// Kernel A (merged): blocks [0,1024): x transpose+bf16 (float4 reads, bf16x4
// packed writes); [1024,1344): weights.
//   x -> XT [B][4096][256] bf16;  w -> Wc [320][256] bf16 (+bc f32[320]).
//   K-side rows get 1/sqrt(32)*log2(e) folded in (softmax runs in exp2).
// ---------------------------------------------------------------------------
__global__ void __launch_bounds__(256) prep_kernel(
    const float* __restrict__ x,
    const float* __restrict__ wq, const float* __restrict__ bq,
    const float* __restrict__ wk, const float* __restrict__ bk,
    const float* __restrict__ wv, const float* __restrict__ bv,
    __hip_bfloat16* __restrict__ Wc, float* __restrict__ bc,
    __hip_bfloat16* __restrict__ XTg)
{
    const int bid = blockIdx.x;
    const int t   = threadIdx.x;
    if (bid >= 1024) {
        const int j = bid - 1024;
        const float kQ = 0.17677669529663687f * 1.4426950408889634f;
        const float* src;
        float sc = 1.0f;
        if (j < 32)       { src = wq + j * 256; }
        else if (j < 64)  { src = wk + (j - 32) * 256; sc = kQ; }
        else              { src = wv + (j - 64) * 256; }
        Wc[j * 256 + t] = __float2bfloat16(src[t] * sc);
        if (t == 0) {
            float bb = (j < 32) ? bq[j] : (j < 64) ? bk[j - 32] * kQ : bv[j - 64];
            bc[j] = bb;
        }
        return;
    }
    __shared__ float xs[64][65];
    const int b  = bid >> 8;
    const int c0 = ((bid >> 6) & 3) * 64;
    const int n0 = (bid & 63) * 64;
    const float* xb = x + ((size_t)b * NCH + c0) * NPIX + n0;
    #pragma unroll
    for (int i = 0; i < 4; ++i) {
        int c  = i * 16 + (t >> 4);
        int n4 = (t & 15) * 4;
        float4 v = *(const float4*)(xb + (size_t)c * NPIX + n4);
        xs[c][n4 + 0] = v.x;
        xs[c][n4 + 1] = v.y;
        xs[c][n4 + 2] = v.z;
        xs[c][n4 + 3] = v.w;
    }
    __syncthreads();
    #pragma unroll
    for (int i = 0; i < 4; ++i) {
        int nn  = i * 16 + (t >> 4);
        int cL4 = (t & 15) * 4;
        s16x4 w;
        w.x = (short)bfbits(xs[cL4 + 0][nn]);
        w.y = (short)bfbits(xs[cL4 + 1][nn]);
        w.z = (short)bfbits(xs[cL4 + 2][nn]);
        w.w = (short)bfbits(xs[cL4 + 3][nn]);
        *(s16x4*)(XTg + ((size_t)b * NPIX + n0 + nn) * NCH + c0 + cL4) = w;
    }
}

// ---------------------------------------------------------------------------
// Kernel C: QKV projection via MFMA 32x32x16 bf16; OUTPUTS IN FP8 e4m3.
//   Q8,K8: [B][n][32] fp8 (K pre-scaled by 1/sqrt32*log2e).
//   V8 : frag-native [B][n/16][c=256][n%16] fp8 -> 8B/lane PV B-frags.
// grid (32, 5, B) = 640 blocks (~2.5/CU): 2 j-tiles per block.
// ---------------------------------------------------------------------------
__global__ void __launch_bounds__(256) proj_kernel(
    const __hip_bfloat16* __restrict__ Wc, const float* __restrict__ bc,
    const __hip_bfloat16* __restrict__ XTg,
    unsigned char* __restrict__ Q8, unsigned char* __restrict__ K8,
    unsigned char* __restrict__ V8)
{
    const int b    = blockIdx.z;
    const int t    = threadIdx.x;
    const int lane = t & 63;
    const int wid  = t >> 6;
    const int lo   = lane & 31;
    const int hi   = lane >> 5;
    const int n0   = blockIdx.x * 128 + wid * 32;
    const int jb   = blockIdx.y * 2;

    short8 xf[16];
    const __hip_bfloat16* xr = XTg + ((size_t)b * NPIX + n0 + lo) * NCH;
    #pragma unroll
    for (int ks = 0; ks < 16; ++ks)
        xf[ks] = *(const short8*)(xr + ks * 16 + hi * 8);

    #pragma unroll
    for (int jo = 0; jo < 2; ++jo) {
        const int jt = jb + jo;
        f32x16 acc;
        #pragma unroll
        for (int r = 0; r < 16; ++r) acc[r] = 0.f;
        const __hip_bfloat16* wr = Wc + (size_t)(jt * 32 + lo) * NCH;
        #pragma unroll
        for (int ks = 0; ks < 16; ++ks) {
            short8 wf = *(const short8*)(wr + ks * 16 + hi * 8);
            acc = __builtin_amdgcn_mfma_f32_32x32x16_bf16(wf, xf[ks], acc, 0, 0, 0);
        }
        if (jt < 2) {
            unsigned char* dst = (jt == 0 ? Q8 : K8)
                               + ((size_t)b * NPIX + n0 + lo) * 32;
            #pragma unroll
            for (int g = 0; g < 4; ++g) {
                int jr = 8 * g + 4 * hi;
                unsigned int w = pkfp8x4(acc[4 * g + 0] + bc[jt * 32 + jr + 0],
                                         acc[4 * g + 1] + bc[jt * 32 + jr + 1],
                                         acc[4 * g + 2] + bc[jt * 32 + jr + 2],
                                         acc[4 * g + 3] + bc[jt * 32 + jr + 3]);
                *(unsigned int*)(dst + jr) = w;
            }
        } else {
            unsigned char* vb = V8 + (size_t)b * NPIX * NCH
                              + (size_t)((n0 + lo) >> 4) * 4096 + (lo & 15);
            #pragma unroll
            for (int r = 0; r < 16; ++r) {
                int jr = (r & 3) + 8 * (r >> 2) + 4 * hi;
                int c  = jt * 32 + jr - 64;
                vb[(size_t)c * 16] = fp8b(acc[r] + bc[jt * 32 + jr]);
            }
        }
    }
}

// ---------------------------------------------------------------------------
// Kernel D: flash attention + residual + LayerNorm. MERGED PHASES, register-
// disciplined (r7 indexing — correctness-verified there — minus r7's spill):
// 8 phases x 512 m, 1 barrier each. Per phase each wave owns 64 m (two
// 32-m halves, QK_a/QK_b), ps dbuf = 2 x [32 q][512 m] (32 KB), PV = 8x
// K=64 MFMA split into PV-A/PV-B sharing ONE 16-reg vva buffer recycled 3x
// per phase (r7 kept 32 live across the barrier -> 944 MB spill). PV-B LDS
// addresses = rva[16]+256 (granule+32 sets bit 5, above the XOR-swz bits).
// Schedule: QK_a | PV-A(it-1) | vva<-V(it-1)s47 | exp_a | QK_b | PV-B(it-1)
// | vva<-V(it)s03 | exp_b | Kpf | barrier. Peak live ~115 regs < 128 ->
// 4 waves/SIMD kept. Tests the fixed-cost-per-barrier theory (16->8 syncs).
// grid (128, 4), 512 thr, 2 blocks/CU.
// ---------------------------------------------------------------------------
__global__ void __launch_bounds__(512, 4) attn_kernel(
    const unsigned char* __restrict__ Q8, const unsigned char* __restrict__ K8,
    const unsigned char* __restrict__ V8, const __hip_bfloat16* __restrict__ XTg,
    const float* __restrict__ gamma_p, const float* __restrict__ lnw,
    const float* __restrict__ lnb, float* __restrict__ out)
{
    // [0,32768): ps dbuf 2 x [32 q][512 m] fp8, 8B-granule XOR swizzle
    // [0,36864): ybuf[256][36] f32 (epilogue overlay of ps)
    // [36864,37888): red_s [8][32];  [37888,39936): red2 [32 q][8 w][2]
    __shared__ char smem[39936];

    const int t    = threadIdx.x;
    const int lane = t & 63;
    const int wid  = __builtin_amdgcn_readfirstlane(t >> 6);  // wave-uniform
    const int lo   = lane & 31;
    const int hi   = lane >> 5;

    // XCD-aware swizzle: batch b pinned to XCDs {2b, 2b+1}
    const int lid = blockIdx.y * 128 + blockIdx.x;
    const int xcd = lid & 7;
    const int b   = xcd >> 1;
    const int q0  = ((xcd & 1) * 64 + (lid >> 3)) * 32;

    // Q B-frag (K=64, upper 32 k zero-padded): col q=lo, k-byte = hi*8+j
    const unsigned char* Qb = Q8 + ((size_t)b * NPIX + q0) * 32;
    Frag64 qv;
    qv.l[0] = *(const long*)(Qb + lo * 32 + hi * 8);
    qv.l[1] = *(const long*)(Qb + lo * 32 + 16 + hi * 8);
    qv.l[2] = 0; qv.l[3] = 0;

    // K: uniform base; wave owns 64 m/phase: rows m = it*512 + wid*64 + ...
    const unsigned char* Ku = K8 + (size_t)b * NPIX * 32 + wid * 2048;
    const int koff = lo * 32 + hi * 8;
    // V: uniform base + lane-const offset; c = 32*wid + lo
    const unsigned char* Vu = V8 + (size_t)b * NPIX * NCH + wid * 512;
    const int vloff = lo * 16 + hi * 8;

    const int swz = lo & 15;
    // PV read addrs: granule (8s+2p+hi)^swz, row stride 512 B. PV-B = +256.
    unsigned int rva[16];
    #pragma unroll
    for (int s = 0; s < 4; ++s)
        #pragma unroll
        for (int p = 0; p < 4; ++p)
            rva[4 * s + p] = (unsigned)(lo * 512
                           + (((8 * s + 2 * p + hi) ^ swz) << 3));
    // exp write addrs: granule (8*wid+g)^swz, g=0..7 (two 32-m halves)
    unsigned int wva[8];
    #pragma unroll
    for (int g = 0; g < 8; ++g)
        wva[g] = (unsigned)(lo * 512 + 4 * hi
               + (((8 * wid + g) ^ swz) << 3));

    f32x16 acc;
    #pragma unroll
    for (int r = 0; r < 16; ++r) acc[r] = 0.f;
    float s_run = 0.f;   // lane-local partial; cross-half exchange deferred

    // K frags for the wave's two 32-m halves (upper 32 k zero)
    Frag64 ka0, ka1;
    ka0.l[0] = *(const long*)(Ku + koff);
    ka0.l[1] = *(const long*)(Ku + koff + 16);
    ka0.l[2] = 0; ka0.l[3] = 0;
    ka1.l[0] = *(const long*)(Ku + 1024 + koff);
    ka1.l[1] = *(const long*)(Ku + 1024 + koff + 16);
    ka1.l[2] = 0; ka1.l[3] = 0;
    long kB0 = 0, kB1 = 0, kB2 = 0, kB3 = 0;

    // vva: SINGLE 4-frag V buffer (16 regs), recycled 3x per phase
    Frag64 vva[4];
    #pragma unroll
    for (int s = 0; s < 4; ++s)
        #pragma unroll
        for (int p = 0; p < 4; ++p)
            vva[s].l[p] = *(const long*)(Vu + s * 16384 + p * 4096 + vloff);

    // ---- prologue phase 0: QK both halves + exp -> ps[0] ----
    {
        f32x16 sct;
        #pragma unroll
        for (int r = 0; r < 16; ++r) sct[r] = 0.f;
        sct = __builtin_amdgcn_mfma_scale_f32_32x32x64_f8f6f4(
            ka0.v, qv.v, sct, 0, 0, 0, SC1, 0, SC1);
        kB0 = *(const long*)(Ku + 16384 + koff);
        kB1 = *(const long*)(Ku + 16384 + koff + 16);
        kB2 = *(const long*)(Ku + 16384 + 1024 + koff);
        kB3 = *(const long*)(Ku + 16384 + 1024 + koff + 16);
        float psum = 0.f;
        #pragma unroll
        for (int g = 0; g < 4; ++g) {
            float e0 = exp2_raw(sct[4 * g + 0]);
            float e1 = exp2_raw(sct[4 * g + 1]);
            float e2 = exp2_raw(sct[4 * g + 2]);
            float e3 = exp2_raw(sct[4 * g + 3]);
            psum += (e0 + e1) + (e2 + e3);
            *(unsigned int*)(smem + wva[g]) = pkfp8x4(e0, e1, e2, e3);
        }
        #pragma unroll
        for (int r = 0; r < 16; ++r) sct[r] = 0.f;
        sct = __builtin_amdgcn_mfma_scale_f32_32x32x64_f8f6f4(
            ka1.v, qv.v, sct, 0, 0, 0, SC1, 0, SC1);
        #pragma unroll
        for (int g = 0; g < 4; ++g) {
            float e0 = exp2_raw(sct[4 * g + 0]);
            float e1 = exp2_raw(sct[4 * g + 1]);
            float e2 = exp2_raw(sct[4 * g + 2]);
            float e3 = exp2_raw(sct[4 * g + 3]);
            psum += (e0 + e1) + (e2 + e3);
            *(unsigned int*)(smem + wva[4 + g]) = pkfp8x4(e0, e1, e2, e3);
        }
        s_run += psum;
    }
    barrier_nodrain();

    // ---- pipelined phases 1..7 ----
    for (int it = 1; it < 8; ++it) {
        #pragma unroll
        for (int g = 0; g < 8; ++g) wva[g] ^= 16384u;

        ka0.l[0] = kB0; ka0.l[1] = kB1;
        ka1.l[0] = kB2; ka1.l[1] = kB3;

        // QK_a(it)
        f32x16 sct;
        #pragma unroll
        for (int r = 0; r < 16; ++r) sct[r] = 0.f;
        sct = __builtin_amdgcn_mfma_scale_f32_32x32x64_f8f6f4(
            ka0.v, qv.v, sct, 0, 0, 0, SC1, 0, SC1);

        // PV-A(it-1): s=0..3, vva = V(it-1) s0..3
        __builtin_amdgcn_s_setprio(1);
        #pragma unroll
        for (int s = 0; s < 4; ++s) {
            Frag64 pa;
            #pragma unroll
            for (int p = 0; p < 4; ++p)
                pa.l[p] = *(const long*)(smem + rva[4 * s + p]);
            acc = __builtin_amdgcn_mfma_scale_f32_32x32x64_f8f6f4(
                pa.v, vva[s].v, acc, 0, 0, 0, SC1, 0, SC1);
        }
        __builtin_amdgcn_s_setprio(0);

        // refill vva <- V(it-1) s=4..7 (consumed by PV-B below)
        {
            const unsigned char* vb1 = Vu + (size_t)(it - 1) * 131072 + 65536;
            #pragma unroll
            for (int s = 0; s < 4; ++s)
                #pragma unroll
                for (int p = 0; p < 4; ++p)
                    vva[s].l[p] = *(const long*)(vb1 + s * 16384 + p * 4096 + vloff);
        }

        // exp_a -> ps[it&1] granules 8wid..+3 (hides V-load latency)
        float psum = 0.f;
        #pragma unroll
        for (int g = 0; g < 4; ++g) {
            float e0 = exp2_raw(sct[4 * g + 0]);
            float e1 = exp2_raw(sct[4 * g + 1]);
            float e2 = exp2_raw(sct[4 * g + 2]);
            float e3 = exp2_raw(sct[4 * g + 3]);
            psum += (e0 + e1) + (e2 + e3);
            *(unsigned int*)(smem + wva[g]) = pkfp8x4(e0, e1, e2, e3);
        }

        // QK_b(it) (latency hidden under PV-B)
        #pragma unroll
        for (int r = 0; r < 16; ++r) sct[r] = 0.f;
        sct = __builtin_amdgcn_mfma_scale_f32_32x32x64_f8f6f4(
            ka1.v, qv.v, sct, 0, 0, 0, SC1, 0, SC1);

        // PV-B(it-1): s=4..7 at rva+256 (granule+32)
        __builtin_amdgcn_s_setprio(1);
        #pragma unroll
        for (int s = 0; s < 4; ++s) {
            Frag64 pa;
            #pragma unroll
            for (int p = 0; p < 4; ++p)
                pa.l[p] = *(const long*)(smem + rva[4 * s + p] + 256);
            acc = __builtin_amdgcn_mfma_scale_f32_32x32x64_f8f6f4(
                pa.v, vva[s].v, acc, 0, 0, 0, SC1, 0, SC1);
        }
        __builtin_amdgcn_s_setprio(0);

        // refill vva <- V(it) s=0..3 (lands across the barrier, no drain)
        {
            const unsigned char* vb0 = Vu + (size_t)it * 131072;
            #pragma unroll
            for (int s = 0; s < 4; ++s)
                #pragma unroll
                for (int p = 0; p < 4; ++p)
                    vva[s].l[p] = *(const long*)(vb0 + s * 16384 + p * 4096 + vloff);
        }

        // exp_b -> ps[it&1] granules 8wid+4..+7
        #pragma unroll
        for (int g = 0; g < 4; ++g) {
            float e0 = exp2_raw(sct[4 * g + 0]);
            float e1 = exp2_raw(sct[4 * g + 1]);
            float e2 = exp2_raw(sct[4 * g + 2]);
            float e3 = exp2_raw(sct[4 * g + 3]);
            psum += (e0 + e1) + (e2 + e3);
            *(unsigned int*)(smem + wva[4 + g]) = pkfp8x4(e0, e1, e2, e3);
        }
        s_run += psum;

        // K prefetch it+1
        if (it < 7) {
            const unsigned char* kn = Ku + (size_t)(it + 1) * 16384;
            kB0 = *(const long*)(kn + koff);
            kB1 = *(const long*)(kn + koff + 16);
            kB2 = *(const long*)(kn + 1024 + koff);
            kB3 = *(const long*)(kn + 1024 + koff + 16);
        }

        barrier_nodrain();

        #pragma unroll
        for (int i = 0; i < 16; ++i) rva[i] ^= 16384u;
    }

    // ---- tail: PV(7) from ps[1] (rva toggled 7x -> parity 1) ----
    {
        __builtin_amdgcn_s_setprio(1);
        #pragma unroll
        for (int s = 0; s < 4; ++s) {
            Frag64 pa;
            #pragma unroll
            for (int p = 0; p < 4; ++p)
                pa.l[p] = *(const long*)(smem + rva[4 * s + p]);
            acc = __builtin_amdgcn_mfma_scale_f32_32x32x64_f8f6f4(
                pa.v, vva[s].v, acc, 0, 0, 0, SC1, 0, SC1);
        }
        __builtin_amdgcn_s_setprio(0);
        const unsigned char* vb1 = Vu + (size_t)7 * 131072 + 65536;
        #pragma unroll
        for (int s = 0; s < 4; ++s)
            #pragma unroll
            for (int p = 0; p < 4; ++p)
                vva[s].l[p] = *(const long*)(vb1 + s * 16384 + p * 4096 + vloff);
        __builtin_amdgcn_s_setprio(1);
        #pragma unroll
        for (int s = 0; s < 4; ++s) {
            Frag64 pa;
            #pragma unroll
            for (int p = 0; p < 4; ++p)
                pa.l[p] = *(const long*)(smem + rva[4 * s + p] + 256);
            acc = __builtin_amdgcn_mfma_scale_f32_32x32x64_f8f6f4(
                pa.v, vva[s].v, acc, 0, 0, 0, SC1, 0, SC1);
        }
        __builtin_amdgcn_s_setprio(0);
    }

    // deferred cross-half softmax-sum exchange
    s_run += __shfl_xor(s_run, 32);

    // ---- epilogue ----
    float* red_sp = (float*)(smem + 36864);       // [8][32]
    float* red2p  = (float*)(smem + 37888);       // [32 q][8 w][2]
    float (*ybuf)[36] = (float(*)[36])smem;       // overlays ps

    if (hi == 0) red_sp[wid * 32 + lo] = s_run;
    __syncthreads();
    float stot = 0.f;
    #pragma unroll
    for (int w = 0; w < 8; ++w) stot += red_sp[w * 32 + lo];
    const float invs = 1.0f / stot;
    const float gamma = gamma_p[0];
    const int cL = 32 * wid + lo;
    const __hip_bfloat16* XTb = XTg + ((size_t)b * NPIX + q0) * NCH + cL;
    float rv[16];
    #pragma unroll
    for (int r = 0; r < 16; ++r) {
        int qr = (r & 3) + 8 * (r >> 2) + 4 * hi;
        float ir = bperm(qr, invs);
        float xv = __bfloat162float(XTb[(size_t)qr * NCH]);
        rv[r] = gamma * (acc[r] * ir) + xv;
        float s1 = rv[r];
        float s2 = rv[r] * rv[r];
        #pragma unroll
        for (int off = 1; off < 32; off <<= 1) {
            s1 += __shfl_xor(s1, off);
            s2 += __shfl_xor(s2, off);
        }
        if (lo == 0) {
            red2p[qr * 16 + wid * 2]     = s1;
            red2p[qr * 16 + wid * 2 + 1] = s2;
        }
    }
    __syncthreads();
    float sA = 0.f, sB = 0.f;
    #pragma unroll
    for (int w = 0; w < 8; ++w) {
        sA += red2p[lo * 16 + w * 2];
        sB += red2p[lo * 16 + w * 2 + 1];
    }
    const float mean = sA * (1.f / 256.f);
    const float var  = sB * (1.f / 256.f) - mean * mean;
    const float rstd = rsqrtf(var + 1e-5f);
    const float lwv = lnw[cL];
    const float lbv = lnb[cL];
    #pragma unroll
    for (int r = 0; r < 16; ++r) {
        int qr = (r & 3) + 8 * (r >> 2) + 4 * hi;
        float m  = bperm(qr, mean);
        float rr = bperm(qr, rstd);
        ybuf[cL][qr] = (rv[r] - m) * rr * lwv + lbv;
    }
    __syncthreads();
    // coalesced store: thread pair per c-row, 16 q's each
    const int c_r = t >> 1;
    const int qh  = (t & 1) * 16;
    float* dst = out + ((size_t)b * NCH + c_r) * NPIX + q0 + qh;
    #pragma unroll
    for (int j = 0; j < 4; ++j) {
        float4 v;
        v.x = ybuf[c_r][qh + j * 4 + 0];
        v.y = ybuf[c_r][qh + j * 4 + 1];
        v.z = ybuf[c_r][qh + j * 4 + 2];
        v.w = ybuf[c_r][qh + j * 4 + 3];
        *(float4*)(dst + j * 4) = v;
    }
}

// ---------------------------------------------------------------------------
extern "C" void kernel_launch(void* const* d_in, const int* in_sizes, int n_in,
                              void* d_out, int out_size, void* d_ws, size_t ws_size,
                              hipStream_t stream) {
    const float* x     = (const float*)d_in[0];
    const float* wq    = (const float*)d_in[1];
    const float* bq    = (const float*)d_in[2];
    const float* wk    = (const float*)d_in[3];
    const float* bk    = (const float*)d_in[4];
    const float* wv    = (const float*)d_in[5];
    const float* bv    = (const float*)d_in[6];
    const float* gamma = (const float*)d_in[7];
    const float* ln_w  = (const float*)d_in[8];
    const float* ln_b  = (const float*)d_in[9];
    float* out = (float*)d_out;

    const int B = 4;
    unsigned char* ws = (unsigned char*)d_ws;
    unsigned char*  Q8 = ws;                                   // 512 KB
    unsigned char*  K8 = ws + (512u << 10);                    // 512 KB
    unsigned char*  V8 = ws + (1u << 20);                      // 4 MB
    __hip_bfloat16* XT = (__hip_bfloat16*)(ws + (5u << 20));   // 8 MB
    __hip_bfloat16* Wc = (__hip_bfloat16*)(ws + (13u << 20));  // 160 KB
    float*          bc = (float*)(ws + (13u << 20) + 163840);  // 1.25 KB

    prep_kernel<<<dim3(1344), 256, 0, stream>>>(x, wq, bq, wk, bk, wv, bv,
                                                Wc, bc, XT);
    proj_kernel<<<dim3(32, 5, B), 256, 0, stream>>>(Wc, bc, XT, Q8, K8, V8);
    attn_kernel<<<dim3(128, B), 512, 0, stream>>>(Q8, K8, V8, XT, gamma,
                                                  ln_w, ln_b, out);
}

// Round 15
// 85.797 us; speedup vs baseline: 1.3912x; 1.3912x over previous
//
#include <hip/hip_runtime.h>
#include <hip/hip_bf16.h>

#define NPIX 4096
#define NCH  256

typedef __attribute__((ext_vector_type(8))) short short8;
typedef __attribute__((ext_vector_type(4))) short s16x4;
typedef __attribute__((ext_vector_type(16))) float f32x16;
typedef __attribute__((ext_vector_type(8))) int i32x8;

// 4x 8-byte k-chunks -> one K=64 f8f6f4 operand (8 VGPRs)
union Frag64 { long l[4]; i32x8 v; };

#define SC1 0x7F7F7F7F  // E8M0 scale bytes = 127 -> scale 1.0 (all blocks)

// pack 4 f32 -> 4 fp8 e4m3 bytes (OCP on gfx950), byte0=a .. byte3=d
__device__ inline unsigned int pkfp8x4(float a, float b, float c, float d) {
    int w = __builtin_amdgcn_cvt_pk_fp8_f32(a, b, 0, false);
    w = __builtin_amdgcn_cvt_pk_fp8_f32(c, d, w, true);
    return (unsigned int)w;
}

__device__ inline unsigned char fp8b(float a) {
    return (unsigned char)(__builtin_amdgcn_cvt_pk_fp8_f32(a, a, 0, false) & 0xff);
}

__device__ inline float bperm(int srclane, float v) {
    return __int_as_float(__builtin_amdgcn_ds_bpermute(
        srclane << 2, __float_as_int(v)));
}

__device__ inline unsigned short bfbits(float f) {
    __hip_bfloat16 h = __float2bfloat16(f);
    return *reinterpret_cast<unsigned short*>(&h);
}

// Raw hw exp2 (no denormal fixup). MUST be the compiler-visible intrinsic:
// inline-asm v_exp_f32 skips TRANS-hazard s_nop insertion -> NaN (r10).
#if __has_builtin(__builtin_amdgcn_exp2f)
__device__ inline float exp2_raw(float x) { return __builtin_amdgcn_exp2f(x); }
#else
__device__ inline float exp2_raw(float x) { return __builtin_exp2f(x); }
#endif

// Barrier WITHOUT the vmcnt(0) drain __syncthreads would emit: only LDS
// (lgkmcnt) ordering is needed for the ps handoff; global register loads
// stay in flight across phases.
__device__ inline void barrier_nodrain() {
    __builtin_amdgcn_sched_barrier(0);
    asm volatile("s_waitcnt lgkmcnt(0)" ::: "memory");
    __builtin_amdgcn_s_barrier();
    __builtin_amdgcn_sched_barrier(0);
}

// ---------------------------------------------------------------------------
// Kernel A (merged): blocks [0,1024): x transpose+bf16 (float4 reads, bf16x4
// packed writes); [1024,1344): weights.
//   x -> XT [B][4096][256] bf16;  w -> Wc [320][256] bf16 (+bc f32[320]).
//   K-side rows get 1/sqrt(32)*log2(e) folded in (softmax runs in exp2).
// ---------------------------------------------------------------------------
__global__ void __launch_bounds__(256) prep_kernel(
    const float* __restrict__ x,
    const float* __restrict__ wq, const float* __restrict__ bq,
    const float* __restrict__ wk, const float* __restrict__ bk,
    const float* __restrict__ wv, const float* __restrict__ bv,
    __hip_bfloat16* __restrict__ Wc, float* __restrict__ bc,
    __hip_bfloat16* __restrict__ XTg)
{
    const int bid = blockIdx.x;
    const int t   = threadIdx.x;
    if (bid >= 1024) {
        const int j = bid - 1024;
        const float kQ = 0.17677669529663687f * 1.4426950408889634f;
        const float* src;
        float sc = 1.0f;
        if (j < 32)       { src = wq + j * 256; }
        else if (j < 64)  { src = wk + (j - 32) * 256; sc = kQ; }
        else              { src = wv + (j - 64) * 256; }
        Wc[j * 256 + t] = __float2bfloat16(src[t] * sc);
        if (t == 0) {
            float bb = (j < 32) ? bq[j] : (j < 64) ? bk[j - 32] * kQ : bv[j - 64];
            bc[j] = bb;
        }
        return;
    }
    __shared__ float xs[64][65];
    const int b  = bid >> 8;
    const int c0 = ((bid >> 6) & 3) * 64;
    const int n0 = (bid & 63) * 64;
    const float* xb = x + ((size_t)b * NCH + c0) * NPIX + n0;
    #pragma unroll
    for (int i = 0; i < 4; ++i) {
        int c  = i * 16 + (t >> 4);
        int n4 = (t & 15) * 4;
        float4 v = *(const float4*)(xb + (size_t)c * NPIX + n4);
        xs[c][n4 + 0] = v.x;
        xs[c][n4 + 1] = v.y;
        xs[c][n4 + 2] = v.z;
        xs[c][n4 + 3] = v.w;
    }
    __syncthreads();
    #pragma unroll
    for (int i = 0; i < 4; ++i) {
        int nn  = i * 16 + (t >> 4);
        int cL4 = (t & 15) * 4;
        s16x4 w;
        w.x = (short)bfbits(xs[cL4 + 0][nn]);
        w.y = (short)bfbits(xs[cL4 + 1][nn]);
        w.z = (short)bfbits(xs[cL4 + 2][nn]);
        w.w = (short)bfbits(xs[cL4 + 3][nn]);
        *(s16x4*)(XTg + ((size_t)b * NPIX + n0 + nn) * NCH + c0 + cL4) = w;
    }
}

// ---------------------------------------------------------------------------
// Kernel C: QKV projection via MFMA 32x32x16 bf16; OUTPUTS IN FP8 e4m3.
//   Q8,K8: [B][n][32] fp8 (K pre-scaled by 1/sqrt32*log2e).
//   V8 : frag-native [B][n/16][c=256][n%16] fp8 -> 8B/lane PV B-frags.
// grid (32, 5, B) = 640 blocks (~2.5/CU): 2 j-tiles per block.
// ---------------------------------------------------------------------------
__global__ void __launch_bounds__(256) proj_kernel(
    const __hip_bfloat16* __restrict__ Wc, const float* __restrict__ bc,
    const __hip_bfloat16* __restrict__ XTg,
    unsigned char* __restrict__ Q8, unsigned char* __restrict__ K8,
    unsigned char* __restrict__ V8)
{
    const int b    = blockIdx.z;
    const int t    = threadIdx.x;
    const int lane = t & 63;
    const int wid  = t >> 6;
    const int lo   = lane & 31;
    const int hi   = lane >> 5;
    const int n0   = blockIdx.x * 128 + wid * 32;
    const int jb   = blockIdx.y * 2;

    short8 xf[16];
    const __hip_bfloat16* xr = XTg + ((size_t)b * NPIX + n0 + lo) * NCH;
    #pragma unroll
    for (int ks = 0; ks < 16; ++ks)
        xf[ks] = *(const short8*)(xr + ks * 16 + hi * 8);

    #pragma unroll
    for (int jo = 0; jo < 2; ++jo) {
        const int jt = jb + jo;
        f32x16 acc;
        #pragma unroll
        for (int r = 0; r < 16; ++r) acc[r] = 0.f;
        const __hip_bfloat16* wr = Wc + (size_t)(jt * 32 + lo) * NCH;
        #pragma unroll
        for (int ks = 0; ks < 16; ++ks) {
            short8 wf = *(const short8*)(wr + ks * 16 + hi * 8);
            acc = __builtin_amdgcn_mfma_f32_32x32x16_bf16(wf, xf[ks], acc, 0, 0, 0);
        }
        if (jt < 2) {
            unsigned char* dst = (jt == 0 ? Q8 : K8)
                               + ((size_t)b * NPIX + n0 + lo) * 32;
            #pragma unroll
            for (int g = 0; g < 4; ++g) {
                int jr = 8 * g + 4 * hi;
                unsigned int w = pkfp8x4(acc[4 * g + 0] + bc[jt * 32 + jr + 0],
                                         acc[4 * g + 1] + bc[jt * 32 + jr + 1],
                                         acc[4 * g + 2] + bc[jt * 32 + jr + 2],
                                         acc[4 * g + 3] + bc[jt * 32 + jr + 3]);
                *(unsigned int*)(dst + jr) = w;
            }
        } else {
            unsigned char* vb = V8 + (size_t)b * NPIX * NCH
                              + (size_t)((n0 + lo) >> 4) * 4096 + (lo & 15);
            #pragma unroll
            for (int r = 0; r < 16; ++r) {
                int jr = (r & 3) + 8 * (r >> 2) + 4 * hi;
                int c  = jt * 32 + jr - 64;
                vb[(size_t)c * 16] = fp8b(acc[r] + bc[jt * 32 + jr]);
            }
        }
    }
}

// ---------------------------------------------------------------------------
// Kernel D: flash attention + residual + LayerNorm. FINAL (r13 == best
// measured: attn 61.7 us, total 86.0 us). r11 VALU-slimmed 16-phase
// lockstep + deferred softmax-sum exchange. Per-wave live state ~128
// unified regs == the feasibility boundary of this dataflow: r7/r12/r14
// (more state or fewer regs) all spill 100-900 MB; r3/r6 (fewer waves)
// lose 2x to latency. 4 waves/SIMD, 2 blocks/CU. grid (128, 4).
// ---------------------------------------------------------------------------
__global__ void __launch_bounds__(512, 4) attn_kernel(
    const unsigned char* __restrict__ Q8, const unsigned char* __restrict__ K8,
    const unsigned char* __restrict__ V8, const __hip_bfloat16* __restrict__ XTg,
    const float* __restrict__ gamma_p, const float* __restrict__ lnw,
    const float* __restrict__ lnb, float* __restrict__ out)
{
    // [0,16384): ps dbuf 2 x [32 q][256 m] fp8, 8B-granule XOR swizzle
    // [0,36864): ybuf[256][36] f32 (epilogue overlay of ps)
    // [36864,37888): red_s [8][32];  [37888,39936): red2 [32 q][8 w][2]
    __shared__ char smem[39936];

    const int t    = threadIdx.x;
    const int lane = t & 63;
    const int wid  = __builtin_amdgcn_readfirstlane(t >> 6);  // wave-uniform
    const int lo   = lane & 31;
    const int hi   = lane >> 5;

    // XCD-aware swizzle: batch b pinned to XCDs {2b, 2b+1}
    const int lid = blockIdx.y * 128 + blockIdx.x;
    const int xcd = lid & 7;
    const int b   = xcd >> 1;
    const int q0  = ((xcd & 1) * 64 + (lid >> 3)) * 32;

    // Q B-frag (K=64, upper 32 k zero-padded): col q=lo, k-byte = hi*8+j
    const unsigned char* Qb = Q8 + ((size_t)b * NPIX + q0) * 32;
    Frag64 qv;
    qv.l[0] = *(const long*)(Qb + lo * 32 + hi * 8);
    qv.l[1] = *(const long*)(Qb + lo * 32 + 16 + hi * 8);
    qv.l[2] = 0; qv.l[3] = 0;

    // K: uniform base (b, wid uniform) + lane-const offset; phase -> +8192
    const unsigned char* Ku = K8 + (size_t)b * NPIX * 32 + wid * 1024;
    const int koff = lo * 32 + hi * 8;
    // V: uniform base + lane-const offset; load (s,p) at +(4s+p)*4096,
    // phase it at +it*65536
    const unsigned char* Vu = V8 + (size_t)b * NPIX * NCH + wid * 512;
    const int vloff = lo * 16 + hi * 8;

    // Hoisted LDS byte-addresses (lane-resident, parity via ^8192 sweeps).
    unsigned int rva[16];
    #pragma unroll
    for (int s = 0; s < 4; ++s)
        #pragma unroll
        for (int p = 0; p < 4; ++p)
            rva[4 * s + p] = (unsigned)(lo * 256
                           + (((8 * s + 2 * p + hi) ^ (lo & 15)) << 3));
    unsigned int wva[4];
    #pragma unroll
    for (int g = 0; g < 4; ++g)
        wva[g] = (unsigned)(lo * 256 + 4 * hi
               + (((4 * wid + g) ^ (lo & 15)) << 3));

    f32x16 acc;
    #pragma unroll
    for (int r = 0; r < 16; ++r) acc[r] = 0.f;
    float s_run = 0.f;   // lane-local partial; cross-half exchange deferred

    // K frag (persistent, upper 32 k zero)
    Frag64 ka;
    ka.l[0] = *(const long*)(Ku + koff);
    ka.l[1] = *(const long*)(Ku + koff + 16);
    ka.l[2] = 0; ka.l[3] = 0;
    long kB0 = 0, kB1 = 0;

    // V frags for phase 0
    Frag64 vva[4];
    #pragma unroll
    for (int s = 0; s < 4; ++s)
        #pragma unroll
        for (int p = 0; p < 4; ++p)
            vva[s].l[p] = *(const long*)(Vu + (4 * s + p) * 4096 + vloff);

    // ---- prologue phase 0: QK(0) + exp(0) -> ps[0] ----
    {
        f32x16 sct;
        #pragma unroll
        for (int r = 0; r < 16; ++r) sct[r] = 0.f;
        sct = __builtin_amdgcn_mfma_scale_f32_32x32x64_f8f6f4(
            ka.v, qv.v, sct, 0, 0, 0, SC1, 0, SC1);
        kB0 = *(const long*)(Ku + 8192 + koff);
        kB1 = *(const long*)(Ku + 8192 + koff + 16);
        float psum = 0.f;
        #pragma unroll
        for (int g = 0; g < 4; ++g) {
            float e0 = exp2_raw(sct[4 * g + 0]);
            float e1 = exp2_raw(sct[4 * g + 1]);
            float e2 = exp2_raw(sct[4 * g + 2]);
            float e3 = exp2_raw(sct[4 * g + 3]);
            psum += (e0 + e1) + (e2 + e3);
            *(unsigned int*)(smem + wva[g]) = pkfp8x4(e0, e1, e2, e3);
        }
        s_run += psum;   // no per-phase shfl (deferred to epilogue)
    }
    barrier_nodrain();

    // ---- pipelined phases 1..15: QK(it) || PV(it-1), exp(it), V(it) ----
    for (int it = 1; it < 16; ++it) {
        // write-parity -> it&1
        #pragma unroll
        for (int g = 0; g < 4; ++g) wva[g] ^= 8192u;

        ka.l[0] = kB0; ka.l[1] = kB1;
        f32x16 sct;
        #pragma unroll
        for (int r = 0; r < 16; ++r) sct[r] = 0.f;
        sct = __builtin_amdgcn_mfma_scale_f32_32x32x64_f8f6f4(
            ka.v, qv.v, sct, 0, 0, 0, SC1, 0, SC1);

        // PV(it-1): pa from ps[(it-1)&1] (rva parity), B = vva (regs)
        __builtin_amdgcn_s_setprio(1);
        #pragma unroll
        for (int s = 0; s < 4; ++s) {
            Frag64 pa;
            #pragma unroll
            for (int p = 0; p < 4; ++p)
                pa.l[p] = *(const long*)(smem + rva[4 * s + p]);
            acc = __builtin_amdgcn_mfma_scale_f32_32x32x64_f8f6f4(
                pa.v, vva[s].v, acc, 0, 0, 0, SC1, 0, SC1);
        }
        __builtin_amdgcn_s_setprio(0);

        // K prefetch for it+1 (uniform base arithmetic)
        if (it < 15) {
            const unsigned char* kn = Ku + (size_t)(it + 1) * 8192;
            kB0 = *(const long*)(kn + koff);
            kB1 = *(const long*)(kn + koff + 16);
        }

        // V(it) loads (uniform base + lane offset; land across the barrier)
        const unsigned char* vit = Vu + (size_t)it * 65536;
        #pragma unroll
        for (int s = 0; s < 4; ++s)
            #pragma unroll
            for (int p = 0; p < 4; ++p)
                vva[s].l[p] = *(const long*)(vit + (4 * s + p) * 4096 + vloff);

        // exp(it) -> ps[it&1]
        float psum = 0.f;
        #pragma unroll
        for (int g = 0; g < 4; ++g) {
            float e0 = exp2_raw(sct[4 * g + 0]);
            float e1 = exp2_raw(sct[4 * g + 1]);
            float e2 = exp2_raw(sct[4 * g + 2]);
            float e3 = exp2_raw(sct[4 * g + 3]);
            psum += (e0 + e1) + (e2 + e3);
            *(unsigned int*)(smem + wva[g]) = pkfp8x4(e0, e1, e2, e3);
        }
        s_run += psum;   // no per-phase shfl (deferred)

        barrier_nodrain();

        // read-parity -> it&1 (consumed next phase / tail)
        #pragma unroll
        for (int i = 0; i < 16; ++i) rva[i] ^= 8192u;
    }

    // ---- tail: PV(15) from ps[1] (rva parity = 1 after 15 toggles) ----
    {
        __builtin_amdgcn_s_setprio(1);
        #pragma unroll
        for (int s = 0; s < 4; ++s) {
            Frag64 pa;
            #pragma unroll
            for (int p = 0; p < 4; ++p)
                pa.l[p] = *(const long*)(smem + rva[4 * s + p]);
            acc = __builtin_amdgcn_mfma_scale_f32_32x32x64_f8f6f4(
                pa.v, vva[s].v, acc, 0, 0, 0, SC1, 0, SC1);
        }
        __builtin_amdgcn_s_setprio(0);
    }

    // deferred cross-half softmax-sum exchange (single DS op, off the
    // per-phase critical path)
    s_run += __shfl_xor(s_run, 32);

    // ---- epilogue ----
    float* red_sp = (float*)(smem + 36864);       // [8][32]
    float* red2p  = (float*)(smem + 37888);       // [32 q][8 w][2]
    float (*ybuf)[36] = (float(*)[36])smem;       // overlays ps

    if (hi == 0) red_sp[wid * 32 + lo] = s_run;
    __syncthreads();
    float stot = 0.f;
    #pragma unroll
    for (int w = 0; w < 8; ++w) stot += red_sp[w * 32 + lo];
    const float invs = 1.0f / stot;
    const float gamma = gamma_p[0];
    const int cL = 32 * wid + lo;
    const __hip_bfloat16* XTb = XTg + ((size_t)b * NPIX + q0) * NCH + cL;
    float rv[16];
    #pragma unroll
    for (int r = 0; r < 16; ++r) {
        int qr = (r & 3) + 8 * (r >> 2) + 4 * hi;
        float ir = bperm(qr, invs);
        float xv = __bfloat162float(XTb[(size_t)qr * NCH]);
        rv[r] = gamma * (acc[r] * ir) + xv;
        float s1 = rv[r];
        float s2 = rv[r] * rv[r];
        #pragma unroll
        for (int off = 1; off < 32; off <<= 1) {
            s1 += __shfl_xor(s1, off);
            s2 += __shfl_xor(s2, off);
        }
        if (lo == 0) {
            red2p[qr * 16 + wid * 2]     = s1;
            red2p[qr * 16 + wid * 2 + 1] = s2;
        }
    }
    __syncthreads();
    float sA = 0.f, sB = 0.f;
    #pragma unroll
    for (int w = 0; w < 8; ++w) {
        sA += red2p[lo * 16 + w * 2];
        sB += red2p[lo * 16 + w * 2 + 1];
    }
    const float mean = sA * (1.f / 256.f);
    const float var  = sB * (1.f / 256.f) - mean * mean;
    const float rstd = rsqrtf(var + 1e-5f);
    const float lwv = lnw[cL];
    const float lbv = lnb[cL];
    #pragma unroll
    for (int r = 0; r < 16; ++r) {
        int qr = (r & 3) + 8 * (r >> 2) + 4 * hi;
        float m  = bperm(qr, mean);
        float rr = bperm(qr, rstd);
        ybuf[cL][qr] = (rv[r] - m) * rr * lwv + lbv;
    }
    __syncthreads();
    // coalesced store: thread pair per c-row, 16 q's each
    const int c_r = t >> 1;
    const int qh  = (t & 1) * 16;
    float* dst = out + ((size_t)b * NCH + c_r) * NPIX + q0 + qh;
    #pragma unroll
    for (int j = 0; j < 4; ++j) {
        float4 v;
        v.x = ybuf[c_r][qh + j * 4 + 0];
        v.y = ybuf[c_r][qh + j * 4 + 1];
        v.z = ybuf[c_r][qh + j * 4 + 2];
        v.w = ybuf[c_r][qh + j * 4 + 3];
        *(float4*)(dst + j * 4) = v;
    }
}

// ---------------------------------------------------------------------------
extern "C" void kernel_launch(void* const* d_in, const int* in_sizes, int n_in,
                              void* d_out, int out_size, void* d_ws, size_t ws_size,
                              hipStream_t stream) {
    const float* x     = (const float*)d_in[0];
    const float* wq    = (const float*)d_in[1];
    const float* bq    = (const float*)d_in[2];
    const float* wk    = (const float*)d_in[3];
    const float* bk    = (const float*)d_in[4];
    const float* wv    = (const float*)d_in[5];
    const float* bv    = (const float*)d_in[6];
    const float* gamma = (const float*)d_in[7];
    const float* ln_w  = (const float*)d_in[8];
    const float* ln_b  = (const float*)d_in[9];
    float* out = (float*)d_out;

    const int B = 4;
    unsigned char* ws = (unsigned char*)d_ws;
    unsigned char*  Q8 = ws;                                   // 512 KB
    unsigned char*  K8 = ws + (512u << 10);                    // 512 KB
    unsigned char*  V8 = ws + (1u << 20);                      // 4 MB
    __hip_bfloat16* XT = (__hip_bfloat16*)(ws + (5u << 20));   // 8 MB
    __hip_bfloat16* Wc = (__hip_bfloat16*)(ws + (13u << 20));  // 160 KB
    float*          bc = (float*)(ws + (13u << 20) + 163840);  // 1.25 KB

    prep_kernel<<<dim3(1344), 256, 0, stream>>>(x, wq, bq, wk, bk, wv, bv,
                                                Wc, bc, XT);
    proj_kernel<<<dim3(32, 5, B), 256, 0, stream>>>(Wc, bc, XT, Q8, K8, V8);
    attn_kernel<<<dim3(128, B), 512, 0, stream>>>(Q8, K8, V8, XT, gamma,
                                                  ln_w, ln_b, out);
}